// Round 5
// baseline (310.985 us; speedup 1.0000x reference)
//
#include <hip/hip_runtime.h>
#include <math.h>

#define NF 128
#define FH 512
#define SQRT_DH 5.656854249492380f
#define LN_EPS 1e-5f

typedef __attribute__((ext_vector_type(8))) short short8;
typedef __attribute__((ext_vector_type(4))) float f32x4;

__device__ __forceinline__ unsigned short f2bf(float x) {
    union { float f; unsigned u; } c; c.f = x;
    unsigned u = c.u;
    return (unsigned short)((u + 0x7fffu + ((u >> 16) & 1u)) >> 16);
}
__device__ __forceinline__ float bf2f(unsigned short h) {
    union { unsigned u; float f; } c; c.u = (unsigned)h << 16; return c.f;
}
__device__ __forceinline__ float lo_bf(unsigned u) {
    union { unsigned u; float f; } c; c.u = u << 16; return c.f;
}
__device__ __forceinline__ float hi_bf(unsigned u) {
    union { unsigned u; float f; } c; c.u = u & 0xffff0000u; return c.f;
}

// ---------------- weight prep ------------------------------------------------
// B-fragment order: frag[kt][nt][lane][i] = W[kt*32 + (lane>>4)*8 + i][nt*16 + (lane&15)]
__global__ __launch_bounds__(256) void prep_w(
    const float* __restrict__ W1, const float* __restrict__ W2,
    const float* __restrict__ Wq, const float* __restrict__ Wk,
    unsigned short* __restrict__ W1f, unsigned short* __restrict__ W2f,
    unsigned short* __restrict__ Wqhi, unsigned short* __restrict__ Wqlo,
    unsigned short* __restrict__ Wkhi, unsigned short* __restrict__ Wklo)
{
    int f = blockIdx.x * 256 + threadIdx.x;   // 0..65535
    int i = f & 7, l = (f >> 3) & 63;
    int lg = l >> 4, l15 = l & 15;
    {
        int ntg = (f >> 9) & 31, kt = f >> 14;
        int k = kt * 32 + lg * 8 + i, n = ntg * 16 + l15;
        W1f[f] = f2bf(W1[k * FH + n]);
    }
    {
        int nt2 = (f >> 9) & 7, kt2 = f >> 12;
        int k = kt2 * 32 + lg * 8 + i, n = nt2 * 16 + l15;
        W2f[f] = f2bf(W2[k * NF + n]);
    }
    if (f < 16384) {
        int nt = (f >> 9) & 7, kt = f >> 12;
        int k = kt * 32 + lg * 8 + i, n = nt * 16 + l15;
        float vq = Wq[k * NF + n];
        unsigned short qh = f2bf(vq);
        Wqhi[f] = qh; Wqlo[f] = f2bf(vq - bf2f(qh));
        float vk = Wk[k * NF + n];
        unsigned short kh = f2bf(vk);
        Wkhi[f] = kh; Wklo[f] = f2bf(vk - bf2f(kh));
    }
}

// ---------------- Kernel 1: q/k projections via MFMA (hi/lo split) ----------
__global__ __launch_bounds__(256) void qk_mfma(
    const float* __restrict__ feat,
    const unsigned short* __restrict__ Wqhi, const unsigned short* __restrict__ Wqlo,
    const unsigned short* __restrict__ Wkhi, const unsigned short* __restrict__ Wklo,
    unsigned* __restrict__ kq, int N)
{
    const int tid = threadIdx.x;
    const int l = tid & 63, wid = tid >> 6;
    const int l15 = l & 15, lg = l >> 4;
    const int n0 = blockIdx.x * 32;

    f32x4 accq[2][2], acck[2][2];
    #pragma unroll
    for (int mf = 0; mf < 2; ++mf)
        #pragma unroll
        for (int nt = 0; nt < 2; ++nt) {
            accq[mf][nt] = (f32x4){0.f, 0.f, 0.f, 0.f};
            acck[mf][nt] = (f32x4){0.f, 0.f, 0.f, 0.f};
        }

    #pragma unroll
    for (int kt = 0; kt < 4; ++kt) {
        short8 ahi[2], alo[2];
        #pragma unroll
        for (int mf = 0; mf < 2; ++mf) {
            int n = n0 + mf * 16 + l15;
            float v[8];
            if (n < N) {
                const float4* p = (const float4*)(feat + (size_t)n * NF + kt * 32 + lg * 8);
                float4 v0 = p[0], v1 = p[1];
                v[0] = v0.x; v[1] = v0.y; v[2] = v0.z; v[3] = v0.w;
                v[4] = v1.x; v[5] = v1.y; v[6] = v1.z; v[7] = v1.w;
            } else {
                #pragma unroll
                for (int i = 0; i < 8; ++i) v[i] = 0.f;
            }
            #pragma unroll
            for (int i = 0; i < 8; ++i) {
                unsigned short h = f2bf(v[i]);
                ahi[mf][i] = (short)h;
                alo[mf][i] = (short)f2bf(v[i] - bf2f(h));
            }
        }
        #pragma unroll
        for (int nt = 0; nt < 2; ++nt) {
            int ntg = wid * 2 + nt;
            size_t fo = ((size_t)(kt * 8 + ntg) * 64 + l) * 8;
            short8 bqh = *(const short8*)(Wqhi + fo);
            short8 bql = *(const short8*)(Wqlo + fo);
            short8 bkh = *(const short8*)(Wkhi + fo);
            short8 bkl = *(const short8*)(Wklo + fo);
            #pragma unroll
            for (int mf = 0; mf < 2; ++mf) {
                accq[mf][nt] = __builtin_amdgcn_mfma_f32_16x16x32_bf16(ahi[mf], bqh, accq[mf][nt], 0, 0, 0);
                accq[mf][nt] = __builtin_amdgcn_mfma_f32_16x16x32_bf16(alo[mf], bqh, accq[mf][nt], 0, 0, 0);
                accq[mf][nt] = __builtin_amdgcn_mfma_f32_16x16x32_bf16(ahi[mf], bql, accq[mf][nt], 0, 0, 0);
                acck[mf][nt] = __builtin_amdgcn_mfma_f32_16x16x32_bf16(ahi[mf], bkh, acck[mf][nt], 0, 0, 0);
                acck[mf][nt] = __builtin_amdgcn_mfma_f32_16x16x32_bf16(alo[mf], bkh, acck[mf][nt], 0, 0, 0);
                acck[mf][nt] = __builtin_amdgcn_mfma_f32_16x16x32_bf16(ahi[mf], bkl, acck[mf][nt], 0, 0, 0);
            }
        }
    }

    #pragma unroll
    for (int mf = 0; mf < 2; ++mf) {
        #pragma unroll
        for (int nt = 0; nt < 2; ++nt) {
            int colg = wid * 32 + nt * 16 + l15;
            #pragma unroll
            for (int r = 0; r < 4; ++r) {
                int n = n0 + mf * 16 + lg * 4 + r;
                if (n < N) {
                    float kk = acck[mf][nt][r];
                    float qq = accq[mf][nt][r];
                    float e = __expf(SQRT_DH * kk);
                    kq[(size_t)n * NF + colg] =
                        ((unsigned)f2bf(qq * e) << 16) | (unsigned)f2bf(e);
                }
            }
        }
    }
}

// ---------------- CSR build ------------------------------------------------
__global__ __launch_bounds__(256) void hist_kernel(
    const int* __restrict__ dst, int* __restrict__ deg, int E)
{
    int i = blockIdx.x * 256 + threadIdx.x;
    if (i < E) atomicAdd(&deg[dst[i]], 1);
}

__global__ __launch_bounds__(1024) void scan_blk(
    const int* __restrict__ deg, int* __restrict__ off,
    int* __restrict__ bsum, int N)
{
    __shared__ int ws[16];
    const int tid = threadIdx.x, lane = tid & 63, w = tid >> 6;
    int i = blockIdx.x * 1024 + tid;
    int v = (i < N) ? deg[i] : 0;
    int x = v;
    #pragma unroll
    for (int o = 1; o < 64; o <<= 1) {
        int t = __shfl_up(x, o);
        if (lane >= o) x += t;
    }
    if (lane == 63) ws[w] = x;
    __syncthreads();
    if (w == 0 && lane < 16) {
        int s = ws[lane];
        #pragma unroll
        for (int o = 1; o < 16; o <<= 1) {
            int t = __shfl_up(s, o);
            if (lane >= o) s += t;
        }
        ws[lane] = s;
    }
    __syncthreads();
    int wbase = (w == 0) ? 0 : ws[w - 1];
    int incl = wbase + x;
    if (i < N) off[i] = incl - v;
    if (tid == 1023) bsum[blockIdx.x] = incl;
}

__global__ __launch_bounds__(64) void scan_mid(int* __restrict__ bsum, int nb)
{
    int lane = threadIdx.x;
    int v = (lane < nb) ? bsum[lane] : 0;
    int x = v;
    #pragma unroll
    for (int o = 1; o < 64; o <<= 1) {
        int t = __shfl_up(x, o);
        if (lane >= o) x += t;
    }
    if (lane < nb) bsum[lane] = x - v;
}

__global__ __launch_bounds__(1024) void scan_add(
    int* __restrict__ off, int* __restrict__ cursor,
    const int* __restrict__ bsum, int N, int E)
{
    int i = blockIdx.x * 1024 + threadIdx.x;
    if (i < N) {
        int o = off[i] + bsum[blockIdx.x];
        off[i] = o; cursor[i] = o;
    }
    if (i == 0) off[N] = E;
}

__global__ __launch_bounds__(256) void scatter_kernel(
    const int* __restrict__ src, const int* __restrict__ dst,
    int* __restrict__ cursor, int* __restrict__ col, int E)
{
    int i = blockIdx.x * 256 + threadIdx.x;
    if (i < E) {
        int pos = atomicAdd(&cursor[dst[i]], 1);
        col[pos] = src[i];
    }
}

// ---------------- gather + residual + LN1 -> xb (bf16), xf (fp32) ----------
__global__ __launch_bounds__(128) void gather_ln1(
    const float* __restrict__ feat, const unsigned* __restrict__ kq,
    const int* __restrict__ off, const int* __restrict__ col,
    const float* __restrict__ ln_g, const float* __restrict__ ln_b,
    unsigned short* __restrict__ xb, float* __restrict__ xf, int N)
{
    __shared__ float sred[2][2];
    const int tid = threadIdx.x;
    const int lane = tid & 63;
    const int wv = tid >> 6;
    const int n0 = blockIdx.x * 8;

    const float gg = ln_g[tid];
    const float bb = ln_b[tid];

    for (int m = 0; m < 8; ++m) {
        int n = n0 + m;
        float xr = 0.f;
        if (n < N) {
            int e0 = off[n], e1 = off[n + 1];
            float d0 = 0.f, q0 = 0.f, d1 = 0.f, q1 = 0.f;
            float d2 = 0.f, q2 = 0.f, d3 = 0.f, q3 = 0.f;
            int e = e0;
            for (; e + 3 < e1; e += 4) {
                unsigned u0 = kq[(size_t)col[e]     * NF + tid];
                unsigned u1 = kq[(size_t)col[e + 1] * NF + tid];
                unsigned u2 = kq[(size_t)col[e + 2] * NF + tid];
                unsigned u3 = kq[(size_t)col[e + 3] * NF + tid];
                d0 += lo_bf(u0); q0 += hi_bf(u0);
                d1 += lo_bf(u1); q1 += hi_bf(u1);
                d2 += lo_bf(u2); q2 += hi_bf(u2);
                d3 += lo_bf(u3); q3 += hi_bf(u3);
            }
            for (; e < e1; ++e) {
                unsigned u = kq[(size_t)col[e] * NF + tid];
                d0 += lo_bf(u); q0 += hi_bf(u);
            }
            d0 += d1 + d2 + d3; q0 += q1 + q2 + q3;
            float ag = (e1 > e0) ? q0 / d0 : 0.f;
            xr = ag + feat[(size_t)n * NF + tid];
        }
        float s1 = xr, s2 = xr * xr;
        #pragma unroll
        for (int o = 32; o > 0; o >>= 1) {
            s1 += __shfl_down(s1, o);
            s2 += __shfl_down(s2, o);
        }
        if (lane == 0) { sred[0][wv] = s1; sred[1][wv] = s2; }
        __syncthreads();
        float mean = (sred[0][0] + sred[0][1]) * (1.f / NF);
        float msq  = (sred[1][0] + sred[1][1]) * (1.f / NF);
        float rs   = rsqrtf(msq - mean * mean + LN_EPS);
        float xv   = (xr - mean) * rs * gg + bb;
        if (n < N) {
            xb[(size_t)n * NF + tid] = f2bf(xv);
            xf[(size_t)n * NF + tid] = xv;
        }
        __syncthreads();
    }
}

// ---------------- fused FFN v2: BM=64, M-split GEMM2, 1 barrier ------------
// GEMM1: wave w -> h cols w*128..+128, rows 0..63 (acc[4][8]).
// h in LDS [64][512] bf16, XOR-swizzled (byte ^= (row&7)<<4).
// GEMM2: wave w -> rows w*16..+16, all 128 cols, K=512 -> LN2 fully in-wave.
__global__ __launch_bounds__(256) void ffn_fused(
    const unsigned short* __restrict__ xb, const float* __restrict__ xf,
    const unsigned short* __restrict__ W1f, const unsigned short* __restrict__ W2f,
    const float* __restrict__ b1, const float* __restrict__ alpha,
    const float* __restrict__ b2,
    const float* __restrict__ ln_g, const float* __restrict__ ln_b,
    float* __restrict__ out, int N)
{
    __shared__ unsigned short hlds[64 * 512];   // 64 KB, swizzled

    const int tid = threadIdx.x;
    const int l = tid & 63;
    const int wid = tid >> 6;
    const int l15 = l & 15;
    const int lg = l >> 4;
    const int n0 = blockIdx.x * 64;

    char* hbase = (char*)hlds;

    // ---- GEMM1: acc[mf][nt], rows n0+mf*16.., cols wid*128+nt*16..
    f32x4 acc[4][8];
    #pragma unroll
    for (int mf = 0; mf < 4; ++mf)
        #pragma unroll
        for (int nt = 0; nt < 8; ++nt)
            acc[mf][nt] = (f32x4){0.f, 0.f, 0.f, 0.f};

    #pragma unroll
    for (int kt = 0; kt < 4; ++kt) {
        short8 a[4];
        #pragma unroll
        for (int mf = 0; mf < 4; ++mf)
            a[mf] = *(const short8*)(xb + (size_t)(n0 + mf * 16 + l15) * NF + kt * 32 + lg * 8);
        #pragma unroll
        for (int nt = 0; nt < 8; ++nt) {
            short8 b = *(const short8*)(W1f + ((kt * 32 + wid * 8 + nt) * 64 + l) * 8);
            #pragma unroll
            for (int mf = 0; mf < 4; ++mf)
                acc[mf][nt] = __builtin_amdgcn_mfma_f32_16x16x32_bf16(a[mf], b, acc[mf][nt], 0, 0, 0);
        }
    }

    // ---- epilogue: + b1, PReLU, -> hlds (swizzled bf16)
    #pragma unroll
    for (int nt = 0; nt < 8; ++nt) {
        int j = wid * 128 + nt * 16 + l15;    // global h col 0..511
        float b1j = b1[j], alj = alpha[j];
        #pragma unroll
        for (int mf = 0; mf < 4; ++mf) {
            #pragma unroll
            for (int r = 0; r < 4; ++r) {
                int row = mf * 16 + lg * 4 + r;
                float hv = acc[mf][nt][r] + b1j;
                hv = hv > 0.f ? hv : alj * hv;
                int byte = row * 1024 + ((j * 2) ^ ((row & 7) << 4));
                *(unsigned short*)(hbase + byte) = f2bf(hv);
            }
        }
    }
    __syncthreads();

    // ---- GEMM2: rows wid*16..+16, cols 0..127, K = 512
    f32x4 acc2[8];
    #pragma unroll
    for (int nt = 0; nt < 8; ++nt)
        acc2[nt] = (f32x4){0.f, 0.f, 0.f, 0.f};

    #pragma unroll
    for (int kt = 0; kt < 16; ++kt) {
        int row = wid * 16 + l15;
        int cb = (kt * 64 + lg * 16) ^ ((row & 7) << 4);
        short8 a = *(const short8*)(hbase + row * 1024 + cb);
        #pragma unroll
        for (int nt = 0; nt < 8; ++nt) {
            short8 b = *(const short8*)(W2f + ((kt * 8 + nt) * 64 + l) * 8);
            acc2[nt] = __builtin_amdgcn_mfma_f32_16x16x32_bf16(a, b, acc2[nt], 0, 0, 0);
        }
    }

    // ---- LN2 fully in-wave: lane holds rows wid*16+lg*4+r, cols l15+16nt
    float b2v[8], ggv[8], bbv[8];
    #pragma unroll
    for (int nt = 0; nt < 8; ++nt) {
        int c = nt * 16 + l15;
        b2v[nt] = b2[c]; ggv[nt] = ln_g[c]; bbv[nt] = ln_b[c];
    }

    #pragma unroll
    for (int r = 0; r < 4; ++r) {
        int row = wid * 16 + lg * 4 + r;
        int n = n0 + row;
        float y[8];
        float s1 = 0.f, s2 = 0.f;
        if (n < N) {
            #pragma unroll
            for (int nt = 0; nt < 8; ++nt) {
                float v = acc2[nt][r] + b2v[nt] + xf[(size_t)n * NF + nt * 16 + l15];
                y[nt] = v; s1 += v; s2 += v * v;
            }
        }
        #pragma unroll
        for (int o = 1; o < 16; o <<= 1) {
            s1 += __shfl_xor(s1, o);
            s2 += __shfl_xor(s2, o);
        }
        float mean = s1 * (1.f / NF);
        float msq  = s2 * (1.f / NF);
        float rs   = rsqrtf(msq - mean * mean + LN_EPS);
        if (n < N) {
            #pragma unroll
            for (int nt = 0; nt < 8; ++nt)
                out[(size_t)n * NF + nt * 16 + l15] = (y[nt] - mean) * rs * ggv[nt] + bbv[nt];
        }
    }
}

// ---------------------------------------------------------------------------
extern "C" void kernel_launch(void* const* d_in, const int* in_sizes, int n_in,
                              void* d_out, int out_size, void* d_ws, size_t ws_size,
                              hipStream_t stream)
{
    const float* feat  = (const float*)d_in[0];
    const float* Wq    = (const float*)d_in[1];
    const float* Wk    = (const float*)d_in[2];
    // d_in[3] = Wv — cancels in per-channel edge softmax, unused.
    const float* ln_g  = (const float*)d_in[4];
    const float* ln_b  = (const float*)d_in[5];
    const float* W1    = (const float*)d_in[6];
    const float* b1    = (const float*)d_in[7];
    const float* alpha = (const float*)d_in[8];
    const float* W2    = (const float*)d_in[9];
    const float* b2    = (const float*)d_in[10];
    const int*   src   = (const int*)d_in[11];
    const int*   dst   = (const int*)d_in[12];

    const int N = in_sizes[0] / NF;
    const int E = in_sizes[11];
    const int Npad = ((N + 63) / 64) * 64;
    float* out = (float*)d_out;

    char* p = (char*)d_ws;
    unsigned*       kq  = (unsigned*)p;       p += (size_t)N * NF * 4;
    unsigned short* xb  = (unsigned short*)p; p += (size_t)Npad * NF * 2;
    float*          xf  = (float*)p;          p += (size_t)Npad * NF * 4;
    unsigned short* W1f = (unsigned short*)p; p += (size_t)NF * FH * 2;
    unsigned short* W2f = (unsigned short*)p; p += (size_t)FH * NF * 2;
    unsigned short* Wqhi = (unsigned short*)p; p += (size_t)NF * NF * 2;
    unsigned short* Wqlo = (unsigned short*)p; p += (size_t)NF * NF * 2;
    unsigned short* Wkhi = (unsigned short*)p; p += (size_t)NF * NF * 2;
    unsigned short* Wklo = (unsigned short*)p; p += (size_t)NF * NF * 2;
    int* deg    = (int*)p;  p += (size_t)N * 4;
    int* off    = (int*)p;  p += (size_t)(N + 1) * 4;
    int* bsum   = (int*)p;  p += 64 * 4;
    int* cursor = (int*)p;  p += (size_t)N * 4;
    int* col    = (int*)p;

    const int nb = (N + 1023) / 1024;

    hipMemsetAsync(deg, 0, (size_t)N * sizeof(int), stream);

    prep_w<<<256, 256, 0, stream>>>(W1, W2, Wq, Wk, W1f, W2f,
                                    Wqhi, Wqlo, Wkhi, Wklo);
    qk_mfma<<<(N + 31) / 32, 256, 0, stream>>>(feat, Wqhi, Wqlo, Wkhi, Wklo,
                                               kq, N);
    hist_kernel<<<(E + 255) / 256, 256, 0, stream>>>(dst, deg, E);
    scan_blk<<<nb, 1024, 0, stream>>>(deg, off, bsum, N);
    scan_mid<<<1, 64, 0, stream>>>(bsum, nb);
    scan_add<<<nb, 1024, 0, stream>>>(off, cursor, bsum, N, E);
    scatter_kernel<<<(E + 255) / 256, 256, 0, stream>>>(src, dst, cursor, col, E);
    gather_ln1<<<(N + 7) / 8, 128, 0, stream>>>(feat, kq, off, col, ln_g, ln_b,
                                                xb, xf, N);
    ffn_fused<<<(N + 63) / 64, 256, 0, stream>>>(xb, xf, W1f, W2f, b1, alpha,
                                                 b2, ln_g, ln_b, out, N);
}

// Round 6
// 264.127 us; speedup vs baseline: 1.1774x; 1.1774x over previous
//
#include <hip/hip_runtime.h>
#include <math.h>

#define NF 128
#define FH 512
#define SQRT_DH 5.656854249492380f
#define LN_EPS 1e-5f

typedef __attribute__((ext_vector_type(8))) short short8;
typedef __attribute__((ext_vector_type(4))) float f32x4;

__device__ __forceinline__ unsigned short f2bf(float x) {
    union { float f; unsigned u; } c; c.f = x;
    unsigned u = c.u;
    return (unsigned short)((u + 0x7fffu + ((u >> 16) & 1u)) >> 16);
}
__device__ __forceinline__ float bf2f(unsigned short h) {
    union { unsigned u; float f; } c; c.u = (unsigned)h << 16; return c.f;
}
__device__ __forceinline__ float lo_bf(unsigned u) {
    union { unsigned u; float f; } c; c.u = u << 16; return c.f;
}
__device__ __forceinline__ float hi_bf(unsigned u) {
    union { unsigned u; float f; } c; c.u = u & 0xffff0000u; return c.f;
}

// ---------------- weight prep ------------------------------------------------
// B-fragment order: frag[kt][nt][lane][i] = W[kt*32 + (lane>>4)*8 + i][nt*16 + (lane&15)]
__global__ __launch_bounds__(256) void prep_w(
    const float* __restrict__ W1, const float* __restrict__ W2,
    const float* __restrict__ Wq, const float* __restrict__ Wk,
    unsigned short* __restrict__ W1f, unsigned short* __restrict__ W2f,
    unsigned short* __restrict__ Wqhi, unsigned short* __restrict__ Wqlo,
    unsigned short* __restrict__ Wkhi, unsigned short* __restrict__ Wklo)
{
    int f = blockIdx.x * 256 + threadIdx.x;   // 0..65535
    int i = f & 7, l = (f >> 3) & 63;
    int lg = l >> 4, l15 = l & 15;
    {
        int ntg = (f >> 9) & 31, kt = f >> 14;
        int k = kt * 32 + lg * 8 + i, n = ntg * 16 + l15;
        W1f[f] = f2bf(W1[k * FH + n]);
    }
    {
        int nt2 = (f >> 9) & 7, kt2 = f >> 12;
        int k = kt2 * 32 + lg * 8 + i, n = nt2 * 16 + l15;
        W2f[f] = f2bf(W2[k * NF + n]);
    }
    if (f < 16384) {
        int nt = (f >> 9) & 7, kt = f >> 12;
        int k = kt * 32 + lg * 8 + i, n = nt * 16 + l15;
        float vq = Wq[k * NF + n];
        unsigned short qh = f2bf(vq);
        Wqhi[f] = qh; Wqlo[f] = f2bf(vq - bf2f(qh));
        float vk = Wk[k * NF + n];
        unsigned short kh = f2bf(vk);
        Wkhi[f] = kh; Wklo[f] = f2bf(vk - bf2f(kh));
    }
}

// ---------------- Kernel 1: q/k projections via MFMA (hi/lo split) ----------
__global__ __launch_bounds__(256) void qk_mfma(
    const float* __restrict__ feat,
    const unsigned short* __restrict__ Wqhi, const unsigned short* __restrict__ Wqlo,
    const unsigned short* __restrict__ Wkhi, const unsigned short* __restrict__ Wklo,
    unsigned* __restrict__ kq, int N)
{
    const int tid = threadIdx.x;
    const int l = tid & 63, wid = tid >> 6;
    const int l15 = l & 15, lg = l >> 4;
    const int n0 = blockIdx.x * 32;

    f32x4 accq[2][2], acck[2][2];
    #pragma unroll
    for (int mf = 0; mf < 2; ++mf)
        #pragma unroll
        for (int nt = 0; nt < 2; ++nt) {
            accq[mf][nt] = (f32x4){0.f, 0.f, 0.f, 0.f};
            acck[mf][nt] = (f32x4){0.f, 0.f, 0.f, 0.f};
        }

    #pragma unroll
    for (int kt = 0; kt < 4; ++kt) {
        short8 ahi[2], alo[2];
        #pragma unroll
        for (int mf = 0; mf < 2; ++mf) {
            int n = n0 + mf * 16 + l15;
            float v[8];
            if (n < N) {
                const float4* p = (const float4*)(feat + (size_t)n * NF + kt * 32 + lg * 8);
                float4 v0 = p[0], v1 = p[1];
                v[0] = v0.x; v[1] = v0.y; v[2] = v0.z; v[3] = v0.w;
                v[4] = v1.x; v[5] = v1.y; v[6] = v1.z; v[7] = v1.w;
            } else {
                #pragma unroll
                for (int i = 0; i < 8; ++i) v[i] = 0.f;
            }
            #pragma unroll
            for (int i = 0; i < 8; ++i) {
                unsigned short h = f2bf(v[i]);
                ahi[mf][i] = (short)h;
                alo[mf][i] = (short)f2bf(v[i] - bf2f(h));
            }
        }
        #pragma unroll
        for (int nt = 0; nt < 2; ++nt) {
            int ntg = wid * 2 + nt;
            size_t fo = ((size_t)(kt * 8 + ntg) * 64 + l) * 8;
            short8 bqh = *(const short8*)(Wqhi + fo);
            short8 bql = *(const short8*)(Wqlo + fo);
            short8 bkh = *(const short8*)(Wkhi + fo);
            short8 bkl = *(const short8*)(Wklo + fo);
            #pragma unroll
            for (int mf = 0; mf < 2; ++mf) {
                accq[mf][nt] = __builtin_amdgcn_mfma_f32_16x16x32_bf16(ahi[mf], bqh, accq[mf][nt], 0, 0, 0);
                accq[mf][nt] = __builtin_amdgcn_mfma_f32_16x16x32_bf16(alo[mf], bqh, accq[mf][nt], 0, 0, 0);
                accq[mf][nt] = __builtin_amdgcn_mfma_f32_16x16x32_bf16(ahi[mf], bql, accq[mf][nt], 0, 0, 0);
                acck[mf][nt] = __builtin_amdgcn_mfma_f32_16x16x32_bf16(ahi[mf], bkh, acck[mf][nt], 0, 0, 0);
                acck[mf][nt] = __builtin_amdgcn_mfma_f32_16x16x32_bf16(alo[mf], bkh, acck[mf][nt], 0, 0, 0);
                acck[mf][nt] = __builtin_amdgcn_mfma_f32_16x16x32_bf16(ahi[mf], bkl, acck[mf][nt], 0, 0, 0);
            }
        }
    }

    #pragma unroll
    for (int mf = 0; mf < 2; ++mf) {
        #pragma unroll
        for (int nt = 0; nt < 2; ++nt) {
            int colg = wid * 32 + nt * 16 + l15;
            #pragma unroll
            for (int r = 0; r < 4; ++r) {
                int n = n0 + mf * 16 + lg * 4 + r;
                if (n < N) {
                    float kk = acck[mf][nt][r];
                    float qq = accq[mf][nt][r];
                    float e = __expf(SQRT_DH * kk);
                    kq[(size_t)n * NF + colg] =
                        ((unsigned)f2bf(qq * e) << 16) | (unsigned)f2bf(e);
                }
            }
        }
    }
}

// ---------------- CSR build ------------------------------------------------
__global__ __launch_bounds__(256) void hist_kernel(
    const int* __restrict__ dst, int* __restrict__ deg, int E)
{
    int i = blockIdx.x * 256 + threadIdx.x;
    if (i < E) atomicAdd(&deg[dst[i]], 1);
}

__global__ __launch_bounds__(1024) void scan_blk(
    const int* __restrict__ deg, int* __restrict__ off,
    int* __restrict__ bsum, int N)
{
    __shared__ int ws[16];
    const int tid = threadIdx.x, lane = tid & 63, w = tid >> 6;
    int i = blockIdx.x * 1024 + tid;
    int v = (i < N) ? deg[i] : 0;
    int x = v;
    #pragma unroll
    for (int o = 1; o < 64; o <<= 1) {
        int t = __shfl_up(x, o);
        if (lane >= o) x += t;
    }
    if (lane == 63) ws[w] = x;
    __syncthreads();
    if (w == 0 && lane < 16) {
        int s = ws[lane];
        #pragma unroll
        for (int o = 1; o < 16; o <<= 1) {
            int t = __shfl_up(s, o);
            if (lane >= o) s += t;
        }
        ws[lane] = s;
    }
    __syncthreads();
    int wbase = (w == 0) ? 0 : ws[w - 1];
    int incl = wbase + x;
    if (i < N) off[i] = incl - v;
    if (tid == 1023) bsum[blockIdx.x] = incl;
}

__global__ __launch_bounds__(64) void scan_mid(int* __restrict__ bsum, int nb)
{
    int lane = threadIdx.x;
    int v = (lane < nb) ? bsum[lane] : 0;
    int x = v;
    #pragma unroll
    for (int o = 1; o < 64; o <<= 1) {
        int t = __shfl_up(x, o);
        if (lane >= o) x += t;
    }
    if (lane < nb) bsum[lane] = x - v;
}

__global__ __launch_bounds__(1024) void scan_add(
    int* __restrict__ off, int* __restrict__ cursor,
    const int* __restrict__ bsum, int N, int E)
{
    int i = blockIdx.x * 1024 + threadIdx.x;
    if (i < N) {
        int o = off[i] + bsum[blockIdx.x];
        off[i] = o; cursor[i] = o;
    }
    if (i == 0) off[N] = E;
}

__global__ __launch_bounds__(256) void scatter_kernel(
    const int* __restrict__ src, const int* __restrict__ dst,
    int* __restrict__ cursor, int* __restrict__ col, int E)
{
    int i = blockIdx.x * 256 + threadIdx.x;
    if (i < E) {
        int pos = atomicAdd(&cursor[dst[i]], 1);
        col[pos] = src[i];
    }
}

// ---------------- gather + residual + LN1 -> xb (bf16), xf (fp32) ----------
__global__ __launch_bounds__(128) void gather_ln1(
    const float* __restrict__ feat, const unsigned* __restrict__ kq,
    const int* __restrict__ off, const int* __restrict__ col,
    const float* __restrict__ ln_g, const float* __restrict__ ln_b,
    unsigned short* __restrict__ xb, float* __restrict__ xf, int N)
{
    __shared__ float sred[2][2];
    const int tid = threadIdx.x;
    const int lane = tid & 63;
    const int wv = tid >> 6;
    const int n0 = blockIdx.x * 8;

    const float gg = ln_g[tid];
    const float bb = ln_b[tid];

    for (int m = 0; m < 8; ++m) {
        int n = n0 + m;
        float xr = 0.f;
        if (n < N) {
            int e0 = off[n], e1 = off[n + 1];
            float d0 = 0.f, q0 = 0.f, d1 = 0.f, q1 = 0.f;
            float d2 = 0.f, q2 = 0.f, d3 = 0.f, q3 = 0.f;
            int e = e0;
            for (; e + 3 < e1; e += 4) {
                unsigned u0 = kq[(size_t)col[e]     * NF + tid];
                unsigned u1 = kq[(size_t)col[e + 1] * NF + tid];
                unsigned u2 = kq[(size_t)col[e + 2] * NF + tid];
                unsigned u3 = kq[(size_t)col[e + 3] * NF + tid];
                d0 += lo_bf(u0); q0 += hi_bf(u0);
                d1 += lo_bf(u1); q1 += hi_bf(u1);
                d2 += lo_bf(u2); q2 += hi_bf(u2);
                d3 += lo_bf(u3); q3 += hi_bf(u3);
            }
            for (; e < e1; ++e) {
                unsigned u = kq[(size_t)col[e] * NF + tid];
                d0 += lo_bf(u); q0 += hi_bf(u);
            }
            d0 += d1 + d2 + d3; q0 += q1 + q2 + q3;
            float ag = (e1 > e0) ? q0 / d0 : 0.f;
            xr = ag + feat[(size_t)n * NF + tid];
        }
        float s1 = xr, s2 = xr * xr;
        #pragma unroll
        for (int o = 32; o > 0; o >>= 1) {
            s1 += __shfl_down(s1, o);
            s2 += __shfl_down(s2, o);
        }
        if (lane == 0) { sred[0][wv] = s1; sred[1][wv] = s2; }
        __syncthreads();
        float mean = (sred[0][0] + sred[0][1]) * (1.f / NF);
        float msq  = (sred[1][0] + sred[1][1]) * (1.f / NF);
        float rs   = rsqrtf(msq - mean * mean + LN_EPS);
        float xv   = (xr - mean) * rs * gg + bb;
        if (n < N) {
            xb[(size_t)n * NF + tid] = f2bf(xv);
            xf[(size_t)n * NF + tid] = xv;
        }
        __syncthreads();
    }
}

// ---------------- fused FFN v3: BM=32, N-split GEMM2, parallel LN, 2 barriers
// GEMM1: wave w -> h cols w*128..+128 (acc[2][8]); h in one shared [32][512]
// bf16 tile, XOR-swizzled (byte ^= (row&7)<<4).
// GEMM2: wave w -> output cols w*32..+32, ALL 32 rows, full K=512 (acc2[2][2]).
// LN2: in-wave 16-lane shfl partials -> sred[32][4] -> broadcast read.
__global__ __launch_bounds__(256) void ffn_fused(
    const unsigned short* __restrict__ xb, const float* __restrict__ xf,
    const unsigned short* __restrict__ W1f, const unsigned short* __restrict__ W2f,
    const float* __restrict__ b1, const float* __restrict__ alpha,
    const float* __restrict__ b2,
    const float* __restrict__ ln_g, const float* __restrict__ ln_b,
    float* __restrict__ out, int N)
{
    __shared__ unsigned short hlds[32 * 512];   // 32 KB, swizzled
    __shared__ float sredS[32][4];
    __shared__ float sredQ[32][4];

    const int tid = threadIdx.x;
    const int l = tid & 63;
    const int wid = tid >> 6;
    const int l15 = l & 15;
    const int lg = l >> 4;
    const int n0 = blockIdx.x * 32;

    char* hbase = (char*)hlds;

    // ---- GEMM1: rows n0..n0+31, wave cols wid*128..+128
    f32x4 acc[2][8];
    #pragma unroll
    for (int mf = 0; mf < 2; ++mf)
        #pragma unroll
        for (int nt = 0; nt < 8; ++nt)
            acc[mf][nt] = (f32x4){0.f, 0.f, 0.f, 0.f};

    #pragma unroll
    for (int kt = 0; kt < 4; ++kt) {
        short8 a0 = *(const short8*)(xb + (size_t)(n0 + l15)      * NF + kt * 32 + lg * 8);
        short8 a1 = *(const short8*)(xb + (size_t)(n0 + 16 + l15) * NF + kt * 32 + lg * 8);
        #pragma unroll
        for (int nt = 0; nt < 8; ++nt) {
            short8 b = *(const short8*)(W1f + ((kt * 32 + wid * 8 + nt) * 64 + l) * 8);
            acc[0][nt] = __builtin_amdgcn_mfma_f32_16x16x32_bf16(a0, b, acc[0][nt], 0, 0, 0);
            acc[1][nt] = __builtin_amdgcn_mfma_f32_16x16x32_bf16(a1, b, acc[1][nt], 0, 0, 0);
        }
    }

    // ---- epilogue: + b1, PReLU, -> hlds (global-j swizzled)
    #pragma unroll
    for (int nt = 0; nt < 8; ++nt) {
        int j = wid * 128 + nt * 16 + l15;    // 0..511
        float b1j = b1[j], alj = alpha[j];
        #pragma unroll
        for (int mf = 0; mf < 2; ++mf) {
            #pragma unroll
            for (int r = 0; r < 4; ++r) {
                int row = mf * 16 + lg * 4 + r;
                float hv = acc[mf][nt][r] + b1j;
                hv = hv > 0.f ? hv : alj * hv;
                int byte = row * 1024 + ((j * 2) ^ ((row & 7) << 4));
                *(unsigned short*)(hbase + byte) = f2bf(hv);
            }
        }
    }
    __syncthreads();

    // ---- prefetch LN2 params + residual (overlaps GEMM2 MFMA)
    const int c0 = wid * 32 + l15;
    const int c1 = c0 + 16;
    const float b20 = b2[c0],  b21 = b2[c1];
    const float gg0 = ln_g[c0], gg1 = ln_g[c1];
    const float bb0 = ln_b[c0], bb1 = ln_b[c1];
    float xv0[2][4], xv1[2][4];
    #pragma unroll
    for (int mf = 0; mf < 2; ++mf)
        #pragma unroll
        for (int r = 0; r < 4; ++r) {
            size_t n = (size_t)(n0 + mf * 16 + lg * 4 + r);
            xv0[mf][r] = xf[n * NF + c0];
            xv1[mf][r] = xf[n * NF + c1];
        }

    // ---- GEMM2: all rows, wave cols wid*32..+32, K = 512
    f32x4 acc2[2][2];
    #pragma unroll
    for (int mf = 0; mf < 2; ++mf)
        #pragma unroll
        for (int nt = 0; nt < 2; ++nt)
            acc2[mf][nt] = (f32x4){0.f, 0.f, 0.f, 0.f};

    #pragma unroll
    for (int kt = 0; kt < 16; ++kt) {
        int jb = kt * 64 + lg * 16;
        int row0 = l15, row1 = 16 + l15;
        short8 a0 = *(const short8*)(hbase + row0 * 1024 + (jb ^ ((row0 & 7) << 4)));
        short8 a1 = *(const short8*)(hbase + row1 * 1024 + (jb ^ ((row1 & 7) << 4)));
        #pragma unroll
        for (int nt = 0; nt < 2; ++nt) {
            short8 b = *(const short8*)(W2f + ((kt * 8 + wid * 2 + nt) * 64 + l) * 8);
            acc2[0][nt] = __builtin_amdgcn_mfma_f32_16x16x32_bf16(a0, b, acc2[0][nt], 0, 0, 0);
            acc2[1][nt] = __builtin_amdgcn_mfma_f32_16x16x32_bf16(a1, b, acc2[1][nt], 0, 0, 0);
        }
    }

    // ---- y = ffn + b2 + x; in-wave partial sums -> sred
    float y0[2][4], y1[2][4];
    #pragma unroll
    for (int mf = 0; mf < 2; ++mf) {
        #pragma unroll
        for (int r = 0; r < 4; ++r) {
            int row = mf * 16 + lg * 4 + r;
            float a = acc2[mf][0][r] + b20 + xv0[mf][r];
            float b = acc2[mf][1][r] + b21 + xv1[mf][r];
            y0[mf][r] = a; y1[mf][r] = b;
            float p1 = a + b, p2 = a * a + b * b;
            #pragma unroll
            for (int o = 1; o < 16; o <<= 1) {
                p1 += __shfl_xor(p1, o);
                p2 += __shfl_xor(p2, o);
            }
            if (l15 == 0) { sredS[row][wid] = p1; sredQ[row][wid] = p2; }
        }
    }
    __syncthreads();

    // ---- LN2 finalize + store
    #pragma unroll
    for (int mf = 0; mf < 2; ++mf) {
        #pragma unroll
        for (int r = 0; r < 4; ++r) {
            int row = mf * 16 + lg * 4 + r;
            int n = n0 + row;
            float S = sredS[row][0] + sredS[row][1] + sredS[row][2] + sredS[row][3];
            float Q = sredQ[row][0] + sredQ[row][1] + sredQ[row][2] + sredQ[row][3];
            float mean = S * (1.f / NF);
            float msq  = Q * (1.f / NF);
            float rs   = rsqrtf(msq - mean * mean + LN_EPS);
            if (n < N) {
                out[(size_t)n * NF + c0] = (y0[mf][r] - mean) * rs * gg0 + bb0;
                out[(size_t)n * NF + c1] = (y1[mf][r] - mean) * rs * gg1 + bb1;
            }
        }
    }
}

// ---------------------------------------------------------------------------
extern "C" void kernel_launch(void* const* d_in, const int* in_sizes, int n_in,
                              void* d_out, int out_size, void* d_ws, size_t ws_size,
                              hipStream_t stream)
{
    const float* feat  = (const float*)d_in[0];
    const float* Wq    = (const float*)d_in[1];
    const float* Wk    = (const float*)d_in[2];
    // d_in[3] = Wv — cancels in per-channel edge softmax, unused.
    const float* ln_g  = (const float*)d_in[4];
    const float* ln_b  = (const float*)d_in[5];
    const float* W1    = (const float*)d_in[6];
    const float* b1    = (const float*)d_in[7];
    const float* alpha = (const float*)d_in[8];
    const float* W2    = (const float*)d_in[9];
    const float* b2    = (const float*)d_in[10];
    const int*   src   = (const int*)d_in[11];
    const int*   dst   = (const int*)d_in[12];

    const int N = in_sizes[0] / NF;
    const int E = in_sizes[11];
    const int Npad = ((N + 63) / 64) * 64;
    float* out = (float*)d_out;

    char* p = (char*)d_ws;
    unsigned*       kq  = (unsigned*)p;       p += (size_t)N * NF * 4;
    unsigned short* xb  = (unsigned short*)p; p += (size_t)Npad * NF * 2;
    float*          xf  = (float*)p;          p += (size_t)Npad * NF * 4;
    unsigned short* W1f = (unsigned short*)p; p += (size_t)NF * FH * 2;
    unsigned short* W2f = (unsigned short*)p; p += (size_t)FH * NF * 2;
    unsigned short* Wqhi = (unsigned short*)p; p += (size_t)NF * NF * 2;
    unsigned short* Wqlo = (unsigned short*)p; p += (size_t)NF * NF * 2;
    unsigned short* Wkhi = (unsigned short*)p; p += (size_t)NF * NF * 2;
    unsigned short* Wklo = (unsigned short*)p; p += (size_t)NF * NF * 2;
    int* deg    = (int*)p;  p += (size_t)N * 4;
    int* off    = (int*)p;  p += (size_t)(N + 1) * 4;
    int* bsum   = (int*)p;  p += 64 * 4;
    int* cursor = (int*)p;  p += (size_t)N * 4;
    int* col    = (int*)p;

    const int nb = (N + 1023) / 1024;

    hipMemsetAsync(deg, 0, (size_t)N * sizeof(int), stream);

    prep_w<<<256, 256, 0, stream>>>(W1, W2, Wq, Wk, W1f, W2f,
                                    Wqhi, Wqlo, Wkhi, Wklo);
    qk_mfma<<<(N + 31) / 32, 256, 0, stream>>>(feat, Wqhi, Wqlo, Wkhi, Wklo,
                                               kq, N);
    hist_kernel<<<(E + 255) / 256, 256, 0, stream>>>(dst, deg, E);
    scan_blk<<<nb, 1024, 0, stream>>>(deg, off, bsum, N);
    scan_mid<<<1, 64, 0, stream>>>(bsum, nb);
    scan_add<<<nb, 1024, 0, stream>>>(off, cursor, bsum, N, E);
    scatter_kernel<<<(E + 255) / 256, 256, 0, stream>>>(src, dst, cursor, col, E);
    gather_ln1<<<(N + 7) / 8, 128, 0, stream>>>(feat, kq, off, col, ln_g, ln_b,
                                                xb, xf, N);
    ffn_fused<<<(N + 31) / 32, 256, 0, stream>>>(xb, xf, W1f, W2f, b1, alpha,
                                                 b2, ln_g, ln_b, out, N);
}